// Round 3
// baseline (711.185 us; speedup 1.0000x reference)
//
#include <hip/hip_runtime.h>

// Problem constants (fixed by setup_inputs)
#define BB 4
#define SS 8
#define CC 3
#define HH 1024
#define WW 1024
#define TH 32
#define TW 64
#define GSH (TH + 8)   // 40 gray rows  (halo 4)
#define GSW (TW + 8)   // 72 gray cols
#define HBH (TH + 8)   // 40 h-blur rows
#define HBW (TW + 4)   // 68 h-blur cols
#define BLH (TH + 4)   // 36 blurred rows (halo 2)
#define BLW (TW + 4)   // 68 blurred cols

__device__ __forceinline__ int refl(int i, int n) {
    // reflect-101 (jnp 'reflect'), valid for i in [-(n-1), 2n-2]
    i = (i < 0) ? -i : i;
    i = (i >= n) ? (2 * n - 2 - i) : i;
    return i;
}

// Hypothesis: np reference = scipy.ndimage-style conv: f64 internal accumulation,
// each stage's output rounded to f32 (gray f32 -> blurred f32 -> lap f32).
__global__ __launch_bounds__(256, 2)
void lap_focus_mixed(const float* __restrict__ x, float* __restrict__ out) {
    const int tile = blockIdx.x;     // 0..2047
    const int b  = tile >> 9;
    const int t  = tile & 511;
    const int tr = t >> 4;
    const int tc = t & 15;
    const int r0 = tr * TH;
    const int c0 = tc * TW;

    __shared__ float  gs[GSH][GSW];  // grayscale (f32, matches np mean output)
    __shared__ double hb[HBH][HBW];  // horizontal Gaussian partial (kept f64)
    __shared__ float  bl[BLH][BLW];  // blurred, rounded to f32 (stage boundary)

    const int tid = threadIdx.x;
    const int tx = tid & 63;
    const int ty = tid >> 6;         // 0..3; thread owns rows ty, ty+4, ..., ty+28

    float best[8];
    int   bidx[8];
#pragma unroll
    for (int m = 0; m < 8; ++m) { best[m] = -3.0e38f; bidx[m] = 0; }

    // g1 = [1,4,6,4,1]/16 — exact dyadics, identical in f32 and f64
    const double GA[5] = {0.0625, 0.25, 0.375, 0.25, 0.0625};
    // Laplacian ksize=5: outer(S,D2)+outer(D2,S) — exact integer weights
    const double LW[5][5] = {
        { 2.,  4.,   4.,  4.,  2.},
        { 4.,  0.,  -8.,  0.,  4.},
        { 4., -8., -24., -8.,  4.},
        { 4.,  0.,  -8.,  0.,  4.},
        { 2.,  4.,   4.,  4.,  2.},
    };

    // column indices into bl for the 5 horizontal lap taps (image-edge reflect)
    int ccol[5];
#pragma unroll
    for (int dj = 0; dj < 5; ++dj)
        ccol[dj] = refl(c0 + tx + dj - 2, WW) - c0 + 2;

    const size_t HW = (size_t)HH * WW;

    for (int s = 0; s < SS; ++s) {
        const float* xs = x + (size_t)((b * SS + s) * CC) * HW;

        // ---- phase 1: grayscale tile + halo(4); f32: ((c0+c1)+c2)/3 (np.mean) ----
        for (int e = tid; e < GSH * GSW; e += 256) {
            int r = e / GSW;
            int c = e - r * GSW;
            int gi = refl(r0 + r - 4, HH);
            int gj = refl(c0 + c - 4, WW);
            size_t off = (size_t)gi * WW + gj;
            float v = (xs[off] + xs[HW + off]) + xs[2 * HW + off];
            gs[r][c] = v / 3.0f;
        }
        __syncthreads();

        // ---- phase 2: horizontal Gaussian, f64 accumulation (no rounding) ----
        for (int e = tid; e < HBH * HBW; e += 256) {
            int r = e / HBW;
            int c = e - r * HBW;
            double acc = 0.0;
#pragma unroll
            for (int j = 0; j < 5; ++j)
                acc += (double)gs[r][c + j] * GA[j];
            hb[r][c] = acc;
        }
        __syncthreads();

        // ---- phase 3: vertical Gaussian, f64 accum -> round to f32 (stage out) ----
        for (int e = tid; e < BLH * BLW; e += 256) {
            int r = e / BLW;
            int c = e - r * BLW;
            double acc = 0.0;
#pragma unroll
            for (int i = 0; i < 5; ++i)
                acc += hb[r + i][c] * GA[i];
            bl[r][c] = (float)acc;   // blurred materialized as f32
        }
        __syncthreads();

        // ---- phase 4: Laplacian, f64 accum over f32 blurred -> f32; argmax ----
#pragma unroll
        for (int m = 0; m < 8; ++m) {
            int i = ty + 4 * m;   // local row
            double acc = 0.0;
#pragma unroll
            for (int di = 0; di < 5; ++di) {
                int rr = refl(r0 + i + di - 2, HH) - r0 + 2;
#pragma unroll
                for (int dj = 0; dj < 5; ++dj) {
                    if (LW[di][dj] != 0.0)
                        acc += (double)bl[rr][ccol[dj]] * LW[di][dj];
                }
            }
            float lap = (float)acc;  // lap materialized as f32
            if (lap > best[m]) { best[m] = lap; bidx[m] = s; }  // first max wins
        }
        __syncthreads();
    }

    // ---- gather: out[b,c,i,j] = x[b, best_s, c, i, j] ----
#pragma unroll
    for (int m = 0; m < 8; ++m) {
        int i = ty + 4 * m;
        int gi = r0 + i;
        int gj = c0 + tx;
        size_t off = (size_t)gi * WW + gj;
        const float* xs = x + (size_t)((b * SS + bidx[m]) * CC) * HW + off;
        float* op = out + (size_t)(b * CC) * HW + off;
        op[0]      = xs[0];
        op[HW]     = xs[HW];
        op[2 * HW] = xs[2 * HW];
    }
}

extern "C" void kernel_launch(void* const* d_in, const int* in_sizes, int n_in,
                              void* d_out, int out_size, void* d_ws, size_t ws_size,
                              hipStream_t stream) {
    (void)in_sizes; (void)n_in; (void)d_ws; (void)ws_size; (void)out_size;
    const float* x = (const float*)d_in[0];
    float* out = (float*)d_out;
    dim3 grid(BB * (HH / TH) * (WW / TW));  // 2048
    dim3 block(256);
    hipLaunchKernelGGL(lap_focus_mixed, grid, block, 0, stream, x, out);
}